// Round 7
// baseline (541.602 us; speedup 1.0000x reference)
//
#include <hip/hip_runtime.h>
#include <math.h>

#define D_ 512
#define M_ 256
#define T_ 128
#define B_ 8
#define TOPK_ 8
#define NH_ 2
#define BT_ (B_*T_)

__device__ __forceinline__ float wred(float v){
#pragma unroll
  for (int m = 1; m < 64; m <<= 1) v += __shfl_xor(v, m, 64);
  return v;
}
__device__ __forceinline__ float4 ld4(const float* p){ return *(const float4*)p; }
__device__ __forceinline__ void st4(float* p, float4 v){ *(float4*)p = v; }
__device__ __forceinline__ float dot4(float4 a, float4 b){
  return a.x*b.x + a.y*b.y + a.z*b.z + a.w*b.w;
}
__device__ __forceinline__ float4 scl4(float4 a, float s){
  a.x*=s; a.y*=s; a.z*=s; a.w*=s; return a;
}

// DPP wave64 sum (VALU-pipe only, no DS traffic).
template<int CTRL>
__device__ __forceinline__ float dpp_add(float x){
  int y = __builtin_amdgcn_update_dpp(0, __float_as_int(x), CTRL, 0xf, 0xf, true);
  return x + __int_as_float(y);
}
__device__ __forceinline__ float wredd(float x){
  x = dpp_add<0x111>(x);   // row_shr:1
  x = dpp_add<0x112>(x);   // row_shr:2
  x = dpp_add<0x114>(x);   // row_shr:4
  x = dpp_add<0x118>(x);   // row_shr:8
  x = dpp_add<0x142>(x);   // row_bcast:15
  x = dpp_add<0x143>(x);   // row_bcast:31
  return __int_as_float(__builtin_amdgcn_readlane(__float_as_int(x), 63));
}

// ---------------------------------------------------------------------------
// A1: addresses + parallel top-8. meta[bt][r] = {widx, ww, dec, ridx}.
// ---------------------------------------------------------------------------
__global__ __launch_bounds__(64) void addr_kernel(
    const float* __restrict__ h, const float* __restrict__ Wk,
    const float* __restrict__ Wq, const float* __restrict__ ltw,
    const float* __restrict__ ltr, const float* __restrict__ gammap,
    float* __restrict__ metab)
{
  const int bt = blockIdx.x;
  const int tid = threadIdx.x;
  __shared__ float p_s[64];

  const float* hrow = h + (size_t)bt*D_;
  const float* wrow = (tid < 32) ? (Wk + (size_t)tid*D_)
                                 : (Wq + (size_t)(tid-32)*D_);
  float dot = 0.f;
  for (int d = 0; d < D_; d += 4){
    float4 hv = ld4(&hrow[d]); float4 wv = ld4(&wrow[d]);
    dot += hv.x*wv.x + hv.y*wv.y + hv.z*wv.z + hv.w*wv.w;
  }
  float tau = (tid < 32) ? expf(ltw[0]) : expf(ltr[0]);
  float mx = dot;
#pragma unroll
  for (int m = 1; m < 16; m <<= 1) mx = fmaxf(mx, __shfl_xor(mx, m, 64));
  float e = expf((dot - mx)/tau);
  float sm = e;
#pragma unroll
  for (int m = 1; m < 16; m <<= 1) sm += __shfl_xor(sm, m, 64);
  p_s[tid] = e / sm;
  __syncthreads();

  const int half = tid >> 5;
  const int l = tid & 31;
  const int g0 = half*32, g1 = half*32 + 16;
  float av[8];
#pragma unroll
  for (int k = 0; k < 8; ++k){
    int x = l*8 + k;
    av[k] = p_s[g0 + (x>>4)] * p_s[g1 + (x&15)];
  }
  const float sp = log1pf(expf(gammap[0]));
  for (int r = 0; r < TOPK_; ++r){
    float bv = -1.f; int bi = 0;
#pragma unroll
    for (int k = 0; k < 8; ++k){ if (av[k] > bv){ bv = av[k]; bi = l*8+k; } }
#pragma unroll
    for (int m = 1; m < 32; m <<= 1){
      float ov = __shfl_xor(bv, m, 64); int oi = __shfl_xor(bi, m, 64);
      if (ov > bv || (ov == bv && oi < bi)){ bv = ov; bi = oi; }
    }
    if ((bi >> 3) == l) av[bi & 7] = -2.f;
    float* mp = metab + (size_t)(bt*TOPK_ + r)*4;
    if (tid == 0){
      mp[0] = __int_as_float(bi); mp[1] = bv; mp[2] = powf(1.f - bv, sp);
    }
    if (tid == 32) mp[3] = __int_as_float(bi);
  }
}

// ---------------------------------------------------------------------------
// A1b: z recurrence precompute (state-independent). Thread m owns zK[m],zV[m].
// Emits zr[bt*8+i] = {1/zK[ri], 1/zV[ri]} (post-update), final o_zK/o_zV.
// ---------------------------------------------------------------------------
__global__ __launch_bounds__(256) void zscan_kernel(
    const float* __restrict__ zK0, const float* __restrict__ zV0,
    const float* __restrict__ metab, float2* __restrict__ zr,
    float* __restrict__ o_zK, float* __restrict__ o_zV)
{
  __shared__ __align__(16) float4 meta_s[T_*TOPK_];
  const int b = blockIdx.x;
  const int m = threadIdx.x;
  const float4* mb = (const float4*)metab + (size_t)b*T_*TOPK_;
#pragma unroll
  for (int q = 0; q < 4; ++q) meta_s[m + q*256] = mb[m + q*256];
  float zk = zK0[b*M_+m], zv = zV0[b*M_+m];
  __syncthreads();
  for (int t = 0; t < T_; ++t){
#pragma unroll
    for (int i = 0; i < TOPK_; ++i){
      float4 me = meta_s[t*TOPK_+i];
      if (m == __float_as_int(me.x)){ zk = me.z*zk + me.y; zv = me.z*zv + me.y; }
    }
#pragma unroll
    for (int i = 0; i < TOPK_; ++i){
      float4 me = meta_s[t*TOPK_+i];
      if (m == __float_as_int(me.w))
        zr[(size_t)(b*T_+t)*TOPK_+i] = make_float2(1.f/zk, 1.f/zv);
    }
  }
  o_zK[b*M_+m] = zk; o_zV[b*M_+m] = zv;
}

// ---------------------------------------------------------------------------
// A2: fp32 NT GEMM, 64x64 tile, batched over grid.z.
// ---------------------------------------------------------------------------
struct GemmPtrs { const float* W[6]; float* C[6]; };

__global__ __launch_bounds__(256) void gemm_nt(
    const float* __restrict__ A, GemmPtrs p)
{
  const float* W = p.W[blockIdx.z];
  float* C = p.C[blockIdx.z];
  const int n0 = blockIdx.x * 64;
  const int m0 = blockIdx.y * 64;
  const int tid = threadIdx.x;
  __shared__ __align__(16) float As[16][68];
  __shared__ __align__(16) float Bs[16][68];
  const int r  = tid >> 2;
  const int c4 = (tid & 3) << 2;
  const int tx4 = (tid & 15) << 2;
  const int ty4 = (tid >> 4) << 2;
  float acc[4][4] = {{0.f}};

  for (int kc = 0; kc < 512; kc += 16){
    float4 av = ld4(&A[(size_t)(m0+r)*512 + kc + c4]);
    float4 wv = ld4(&W[(size_t)(n0+r)*512 + kc + c4]);
    __syncthreads();
    As[c4+0][r]=av.x; As[c4+1][r]=av.y; As[c4+2][r]=av.z; As[c4+3][r]=av.w;
    Bs[c4+0][r]=wv.x; Bs[c4+1][r]=wv.y; Bs[c4+2][r]=wv.z; Bs[c4+3][r]=wv.w;
    __syncthreads();
#pragma unroll
    for (int k = 0; k < 16; ++k){
      float4 a  = ld4(&As[k][ty4]);
      float4 bq = ld4(&Bs[k][tx4]);
      acc[0][0]+=a.x*bq.x; acc[0][1]+=a.x*bq.y; acc[0][2]+=a.x*bq.z; acc[0][3]+=a.x*bq.w;
      acc[1][0]+=a.y*bq.x; acc[1][1]+=a.y*bq.y; acc[1][2]+=a.y*bq.z; acc[1][3]+=a.y*bq.w;
      acc[2][0]+=a.z*bq.x; acc[2][1]+=a.z*bq.y; acc[2][2]+=a.z*bq.z; acc[2][3]+=a.z*bq.w;
      acc[3][0]+=a.w*bq.x; acc[3][1]+=a.w*bq.y; acc[3][2]+=a.w*bq.z; acc[3][3]+=a.w*bq.w;
    }
  }
#pragma unroll
  for (int i = 0; i < 4; ++i){
    float4 cv; cv.x=acc[i][0]; cv.y=acc[i][1]; cv.z=acc[i][2]; cv.w=acc[i][3];
    st4(&C[(size_t)(m0+ty4+i)*512 + n0 + tx4], cv);
  }
}

// ---------------------------------------------------------------------------
// C: fused out = sigmoid(h@Wg.T) * (rdo@Wo.T).
// ---------------------------------------------------------------------------
__global__ __launch_bounds__(256) void gemm_out(
    const float* __restrict__ h, const float* __restrict__ rdo,
    const float* __restrict__ Wg, const float* __restrict__ Wo,
    float* __restrict__ C)
{
  const int n0 = blockIdx.x * 64;
  const int m0 = blockIdx.y * 64;
  const int tid = threadIdx.x;
  __shared__ __align__(16) float Ag[16][68];
  __shared__ __align__(16) float Ao[16][68];
  __shared__ __align__(16) float Bg[16][68];
  __shared__ __align__(16) float Bo[16][68];
  const int r  = tid >> 2;
  const int c4 = (tid & 3) << 2;
  const int tx4 = (tid & 15) << 2;
  const int ty4 = (tid >> 4) << 2;
  float accg[4][4] = {{0.f}};
  float acco[4][4] = {{0.f}};

  for (int kc = 0; kc < 512; kc += 16){
    float4 a1 = ld4(&h  [(size_t)(m0+r)*512 + kc + c4]);
    float4 a2 = ld4(&rdo[(size_t)(m0+r)*512 + kc + c4]);
    float4 w1 = ld4(&Wg [(size_t)(n0+r)*512 + kc + c4]);
    float4 w2 = ld4(&Wo [(size_t)(n0+r)*512 + kc + c4]);
    __syncthreads();
    Ag[c4+0][r]=a1.x; Ag[c4+1][r]=a1.y; Ag[c4+2][r]=a1.z; Ag[c4+3][r]=a1.w;
    Ao[c4+0][r]=a2.x; Ao[c4+1][r]=a2.y; Ao[c4+2][r]=a2.z; Ao[c4+3][r]=a2.w;
    Bg[c4+0][r]=w1.x; Bg[c4+1][r]=w1.y; Bg[c4+2][r]=w1.z; Bg[c4+3][r]=w1.w;
    Bo[c4+0][r]=w2.x; Bo[c4+1][r]=w2.y; Bo[c4+2][r]=w2.z; Bo[c4+3][r]=w2.w;
    __syncthreads();
#pragma unroll
    for (int k = 0; k < 16; ++k){
      float4 ag = ld4(&Ag[k][ty4]);
      float4 ao = ld4(&Ao[k][ty4]);
      float4 bg = ld4(&Bg[k][tx4]);
      float4 bo = ld4(&Bo[k][tx4]);
      accg[0][0]+=ag.x*bg.x; accg[0][1]+=ag.x*bg.y; accg[0][2]+=ag.x*bg.z; accg[0][3]+=ag.x*bg.w;
      accg[1][0]+=ag.y*bg.x; accg[1][1]+=ag.y*bg.y; accg[1][2]+=ag.y*bg.z; accg[1][3]+=ag.y*bg.w;
      accg[2][0]+=ag.z*bg.x; accg[2][1]+=ag.z*bg.y; accg[2][2]+=ag.z*bg.z; accg[2][3]+=ag.z*bg.w;
      accg[3][0]+=ag.w*bg.x; accg[3][1]+=ag.w*bg.y; accg[3][2]+=ag.w*bg.z; accg[3][3]+=ag.w*bg.w;
      acco[0][0]+=ao.x*bo.x; acco[0][1]+=ao.x*bo.y; acco[0][2]+=ao.x*bo.z; acco[0][3]+=ao.x*bo.w;
      acco[1][0]+=ao.y*bo.x; acco[1][1]+=ao.y*bo.y; acco[1][2]+=ao.y*bo.z; acco[1][3]+=ao.y*bo.w;
      acco[2][0]+=ao.z*bo.x; acco[2][1]+=ao.z*bo.y; acco[2][2]+=ao.z*bo.z; acco[2][3]+=ao.z*bo.w;
      acco[3][0]+=ao.w*bo.x; acco[3][1]+=ao.w*bo.y; acco[3][2]+=ao.w*bo.z; acco[3][3]+=ao.w*bo.w;
    }
  }
#pragma unroll
  for (int i = 0; i < 4; ++i){
    float4 cv;
    cv.x = acco[i][0] / (1.f + expf(-accg[i][0]));
    cv.y = acco[i][1] / (1.f + expf(-accg[i][1]));
    cv.z = acco[i][2] / (1.f + expf(-accg[i][2]));
    cv.w = acco[i][3] / (1.f + expf(-accg[i][3]));
    st4(&C[(size_t)(m0+ty4+i)*512 + n0 + tx4], cv);
  }
}

// ---------------------------------------------------------------------------
// A3: fused per-bt elementwise + cross-head precompute.
// khat <- normalized; kvk0 <- ucK = be0*u0K + be1*u1K; kvv0 <- ucV;
// pre2[bt*8+{0..4}] = {c01, dK, dV, be0, be1}.
// ---------------------------------------------------------------------------
__global__ __launch_bounds__(256) void ew2_kernel(
    float* __restrict__ khat, float* __restrict__ kvk, float* __restrict__ kvv,
    float* __restrict__ pre2, const float* __restrict__ h,
    const float* __restrict__ hh_bw, const float* __restrict__ hh_bb)
{
  const int bt = blockIdx.x;
  const int tid = threadIdx.x;
  const int wid = tid >> 6, lane = tid & 63;
  float* k0p  = khat + (size_t)bt*D_;
  float* k1p  = khat + (size_t)BT_*D_ + (size_t)bt*D_;
  float* vk0p = kvk  + (size_t)bt*D_;
  float* vk1p = kvk  + (size_t)BT_*D_ + (size_t)bt*D_;
  float* vv0p = kvv  + (size_t)bt*D_;
  float* vv1p = kvv  + (size_t)BT_*D_ + (size_t)bt*D_;
  const float* hp  = h + (size_t)bt*D_;

  float s0[2], s1[2];
  float n0 = 0.f, n1 = 0.f, bd0 = 0.f, bd1 = 0.f;
#pragma unroll
  for (int q = 0; q < 2; ++q){
    int d = tid + q*256;
    float x0 = k0p[d], x1 = k1p[d], hv = hp[d];
    float v0 = x0 / (1.f + expf(-x0));
    float v1 = x1 / (1.f + expf(-x1));
    s0[q] = v0; s1[q] = v1;
    n0 += v0*v0; n1 += v1*v1;
    bd0 += hv*hh_bw[d]; bd1 += hv*hh_bw[D_ + d];
  }
  __shared__ float4 rb[4];
  float4 acc = make_float4(wred(n0), wred(n1), wred(bd0), wred(bd1));
  if (lane == 0) rb[wid] = acc;
  __syncthreads();
  float4 t0 = rb[0], t1 = rb[1], t2 = rb[2], t3 = rb[3];
  n0 = t0.x+t1.x+t2.x+t3.x; n1 = t0.y+t1.y+t2.y+t3.y;
  bd0 = t0.z+t1.z+t2.z+t3.z; bd1 = t0.w+t1.w+t2.w+t3.w;
  float inv0 = 1.f / fmaxf(sqrtf(n0), 1e-12f);
  float inv1 = 1.f / fmaxf(sqrtf(n1), 1e-12f);
  float be0 = 2.f / (1.f + expf(-(bd0 + hh_bb[0])));
  float be1 = 2.f / (1.f + expf(-(bd1 + hh_bb[1])));

  float c01 = 0.f, dK = 0.f, dV = 0.f;
#pragma unroll
  for (int q = 0; q < 2; ++q){
    int d = tid + q*256;
    float kh0 = s0[q]*inv0, kh1 = s1[q]*inv1;
    float u0K = s0[q]*vk0p[d], u1K = s1[q]*vk1p[d];
    float u0V = s0[q]*vv0p[d], u1V = s1[q]*vv1p[d];
    k0p[d] = kh0; k1p[d] = kh1;
    vk0p[d] = be0*u0K + be1*u1K;
    vv0p[d] = be0*u0V + be1*u1V;
    c01 += kh1*kh0; dK += kh1*u0K; dV += kh1*u0V;
  }
  __syncthreads();
  float4 acc2 = make_float4(wred(c01), wred(dK), wred(dV), 0.f);
  if (lane == 0) rb[wid] = acc2;
  __syncthreads();
  if (tid == 0){
    float4 a = rb[0], b = rb[1], c = rb[2], d = rb[3];
    pre2[(size_t)bt*8+0] = a.x+b.x+c.x+d.x;
    pre2[(size_t)bt*8+1] = a.y+b.y+c.y+d.y;
    pre2[(size_t)bt*8+2] = a.z+b.z+c.z+d.z;
    pre2[(size_t)bt*8+3] = be0;
    pre2[(size_t)bt*8+4] = be1;
  }
}

// ---------------------------------------------------------------------------
// B: sequential scan v6 — ONE barrier per step, no forwarding.
// Phase A(t): ring commit, staged reads, fused 2-head update, global scatter.
// __syncthreads (drains scatters). Phase B(t): fresh read-row + next-state
// loads from global (post-barrier => current), readout(t-1) overlaps load
// latency, resolve(t) writes rel2/Vr (parity buffers, consumed in B(t+1)).
// z handled entirely by zscan_kernel (reciprocals prefetched).
// ---------------------------------------------------------------------------
__global__ __launch_bounds__(512) void scan_kernel(
    float* __restrict__ Ks, float* __restrict__ Vs,
    const float* __restrict__ khat, const float* __restrict__ ucKb,
    const float* __restrict__ ucVb, const float* __restrict__ pre2,
    const float* __restrict__ metab, const float2* __restrict__ zr,
    const float* __restrict__ h, float* __restrict__ readout,
    float* __restrict__ o_widx, float* __restrict__ o_ridx)
{
  __shared__ __align__(16) float ring[4][4*D_];
  __shared__ __align__(16) float Vr_s[2][TOPK_][D_];
  __shared__ float2 rel2_s[2][TOPK_];

  const int b = blockIdx.x;
  const int tid = threadIdx.x;
  const int s = tid >> 6, lane = tid & 63;
  const int l4 = lane * 4;
  const float scale = 0.044194173824159216f;   // 1/sqrt(512)

  float* Ksb = Ks + (size_t)b*M_*D_;
  float* Vsb = Vs + (size_t)b*M_*D_;
  const float* vbt[4] = { khat, khat + (size_t)BT_*D_, ucKb, ucVb };
  const float* srcc = vbt[s >> 1];
  const int goff = (s & 1)*256 + l4;
  const int loff = (s >> 1)*D_ + goff;
  const float4* mb = (const float4*)metab;

  // ---- prologue ----
  const int bt0 = b*T_;
  st4(&ring[0][loff], ld4(srcc + (size_t)bt0*D_ + goff));
  st4(&ring[1][loff], ld4(srcc + (size_t)(bt0+1)*D_ + goff));
  float4 g = ld4(srcc + (size_t)(bt0+2)*D_ + goff);   // committed at A(0)

  float4 me   = mb[bt0*TOPK_ + s];
  float4 me_n = mb[(bt0+1)*TOPK_ + s];
  float4 pm   = ld4(&pre2[(size_t)bt0*8]);
  float  be1v = pre2[(size_t)bt0*8+4];
  float4 pm_n = ld4(&pre2[(size_t)(bt0+1)*8]);
  float  be1_n= pre2[(size_t)(bt0+1)*8+4];
  float2 zr2   = zr[(size_t)bt0*TOPK_ + s];
  float2 zr2_n = zr[(size_t)(bt0+1)*TOPK_ + s];

  int mi = __float_as_int(me.x);
  float4 K0 = ld4(&Ksb[(size_t)mi*D_ + l4]);
  float4 K1 = ld4(&Ksb[(size_t)mi*D_ + 256 + l4]);
  float4 V0 = ld4(&Vsb[(size_t)mi*D_ + l4]);
  float4 V1 = ld4(&Vsb[(size_t)mi*D_ + 256 + l4]);
  __syncthreads();

#pragma unroll 4
  for (int t = 0; t < T_; ++t){
    const int bt = b*T_ + t;
    const float dec = me.z;
    const int   ri  = __float_as_int(me.w);
    mi = __float_as_int(me.x);

    // ---------------- A(t) ----------------
    st4(&ring[(t+2)&3][loff], g);          // commit staged(t+2)
    float4 HTa = ld4(h + (size_t)bt*D_ + l4);          // for B's dot
    float4 HTb = ld4(h + (size_t)bt*D_ + 256 + l4);

    const float* rbuf = ring[t & 3];
    float4 kh0a = ld4(&rbuf[l4]),        kh0b = ld4(&rbuf[256+l4]);
    float4 kh1a = ld4(&rbuf[D_+l4]),     kh1b = ld4(&rbuf[D_+256+l4]);
    float4 ucKa = ld4(&rbuf[2*D_+l4]),   ucKb2 = ld4(&rbuf[2*D_+256+l4]);
    float4 ucVa = ld4(&rbuf[3*D_+l4]),   ucVb2 = ld4(&rbuf[3*D_+256+l4]);

    K0 = scl4(K0,dec); K1 = scl4(K1,dec);
    V0 = scl4(V0,dec); V1 = scl4(V1,dec);
    float aK = wredd(dot4(K0,kh0a) + dot4(K1,kh0b));
    float bK = wredd(dot4(K0,kh1a) + dot4(K1,kh1b));
    float aV = wredd(dot4(V0,kh0a) + dot4(V1,kh0b));
    float bV = wredd(dot4(V0,kh1a) + dot4(V1,kh1b));
    float p0K = pm.w*aK, p1K = be1v*(bK + pm.w*(pm.y - aK*pm.x));
    float p0V = pm.w*aV, p1V = be1v*(bV + pm.w*(pm.z - aV*pm.x));
    K0.x += ucKa.x  - p0K*kh0a.x - p1K*kh1a.x;
    K0.y += ucKa.y  - p0K*kh0a.y - p1K*kh1a.y;
    K0.z += ucKa.z  - p0K*kh0a.z - p1K*kh1a.z;
    K0.w += ucKa.w  - p0K*kh0a.w - p1K*kh1a.w;
    K1.x += ucKb2.x - p0K*kh0b.x - p1K*kh1b.x;
    K1.y += ucKb2.y - p0K*kh0b.y - p1K*kh1b.y;
    K1.z += ucKb2.z - p0K*kh0b.z - p1K*kh1b.z;
    K1.w += ucKb2.w - p0K*kh0b.w - p1K*kh1b.w;
    V0.x += ucVa.x  - p0V*kh0a.x - p1V*kh1a.x;
    V0.y += ucVa.y  - p0V*kh0a.y - p1V*kh1a.y;
    V0.z += ucVa.z  - p0V*kh0a.z - p1V*kh1a.z;
    V0.w += ucVa.w  - p0V*kh0a.w - p1V*kh1a.w;
    V1.x += ucVb2.x - p0V*kh0b.x - p1V*kh1b.x;
    V1.y += ucVb2.y - p0V*kh0b.y - p1V*kh1b.y;
    V1.z += ucVb2.z - p0V*kh0b.z - p1V*kh1b.z;
    V1.w += ucVb2.w - p0V*kh0b.w - p1V*kh1b.w;

    st4(&Ksb[(size_t)mi*D_ + l4], K0); st4(&Ksb[(size_t)mi*D_ + 256 + l4], K1);
    st4(&Vsb[(size_t)mi*D_ + l4], V0); st4(&Vsb[(size_t)mi*D_ + 256 + l4], V1);

    __syncthreads();   // THE barrier: scatters drained & visible everywhere

    // ---------------- B(t) ----------------
    // fresh reads (post-barrier => include update(t))
    float4 RK0 = ld4(&Ksb[(size_t)ri*D_ + l4]);
    float4 RK1 = ld4(&Ksb[(size_t)ri*D_ + 256 + l4]);
    float4 RV0 = ld4(&Vsb[(size_t)ri*D_ + l4]);
    float4 RV1 = ld4(&Vsb[(size_t)ri*D_ + 256 + l4]);
    // state rows for t+1
    const int mi_n = __float_as_int(me_n.x);
    float4 nK0 = ld4(&Ksb[(size_t)mi_n*D_ + l4]);
    float4 nK1 = ld4(&Ksb[(size_t)mi_n*D_ + 256 + l4]);
    float4 nV0 = ld4(&Vsb[(size_t)mi_n*D_ + l4]);
    float4 nV1 = ld4(&Vsb[(size_t)mi_n*D_ + 256 + l4]);
    // staged fill for t+3, meta/pre/zr for t+2
    const int bt3  = (t+3 < T_) ? bt+3 : b*T_+T_-1;
    const int btnn = (t+2 < T_) ? bt+2 : b*T_+T_-1;
    g = ld4(srcc + (size_t)bt3*D_ + goff);
    float4 me_nn = mb[btnn*TOPK_ + s];
    float4 pm_nn = ld4(&pre2[(size_t)btnn*8]);
    float  be1nn = pre2[(size_t)btnn*8+4];
    float2 zr2nn = zr[(size_t)btnn*TOPK_ + s];

    // readout(t-1): overlaps the loads above
    if (t > 0){
      const int pp = (t-1) & 1;
      float2 rz[TOPK_];
#pragma unroll
      for (int i = 0; i < TOPK_; ++i) rz[i] = rel2_s[pp][i];
      float mx = rz[0].x;
#pragma unroll
      for (int i = 1; i < TOPK_; ++i) mx = fmaxf(mx, rz[i].x);
      float smm = 0.f, r = 0.f;
#pragma unroll
      for (int i = 0; i < TOPK_; ++i){
        float ev = __expf(rz[i].x - mx); smm += ev;
        r += ev * rz[i].y * Vr_s[pp][i][tid];
      }
      readout[(size_t)(bt-1)*D_ + tid] = r * __builtin_amdgcn_rcpf(smm);
    }

    // resolve(t): rel2/Vr for parity t&1 (consumed in B(t+1))
    float dt = wredd(dot4(RK0,HTa) + dot4(RK1,HTb));
    if (lane == 0)
      rel2_s[t&1][s] = make_float2(dt * scale * zr2.x, zr2.y);
    st4(&Vr_s[t&1][s][l4], RV0); st4(&Vr_s[t&1][s][256+l4], RV1);

    // rotate pipeline
    K0=nK0; K1=nK1; V0=nV0; V1=nV1;
    me=me_n; pm=pm_n; be1v=be1_n; zr2=zr2_n;
    me_n=me_nn; pm_n=pm_nn; be1_n=be1nn; zr2_n=zr2nn;
  }

  // ---- epilogue: readout(T-1) after a final barrier ----
  __syncthreads();
  {
    const int btL = b*T_ + T_ - 1;
    const int pp = (T_-1) & 1;
    float2 rz[TOPK_];
#pragma unroll
    for (int i = 0; i < TOPK_; ++i) rz[i] = rel2_s[pp][i];
    float mx = rz[0].x;
#pragma unroll
    for (int i = 1; i < TOPK_; ++i) mx = fmaxf(mx, rz[i].x);
    float smm = 0.f, r = 0.f;
#pragma unroll
    for (int i = 0; i < TOPK_; ++i){
      float ev = __expf(rz[i].x - mx); smm += ev;
      r += ev * rz[i].y * Vr_s[pp][i][tid];
    }
    readout[(size_t)btL*D_ + tid] = r * __builtin_amdgcn_rcpf(smm);

    if (tid < TOPK_){
      float4 m = mb[btL*TOPK_ + tid];
      o_widx[b*TOPK_+tid] = (float)__float_as_int(m.x);
      o_ridx[b*TOPK_+tid] = (float)__float_as_int(m.w);
    }
  }
}

// ---------------------------------------------------------------------------
extern "C" void kernel_launch(void* const* d_in, const int* in_sizes, int n_in,
                              void* d_out, int out_size, void* d_ws, size_t ws_size,
                              hipStream_t stream)
{
  (void)in_sizes; (void)n_in; (void)out_size; (void)ws_size;
  const float* h       = (const float*)d_in[0];
  const float* K_slots = (const float*)d_in[1];
  const float* V_slots = (const float*)d_in[2];
  const float* z_K     = (const float*)d_in[3];
  const float* z_V     = (const float*)d_in[4];
  const float* W_k     = (const float*)d_in[5];
  const float* W_q     = (const float*)d_in[6];
  const float* ltw     = (const float*)d_in[7];
  const float* ltr     = (const float*)d_in[8];
  const float* hh_k    = (const float*)d_in[9];
  const float* hh_vk   = (const float*)d_in[10];
  const float* hh_vv   = (const float*)d_in[11];
  const float* hh_bw   = (const float*)d_in[12];
  const float* hh_bb   = (const float*)d_in[13];
  const float* gamma   = (const float*)d_in[14];
  const float* W_out   = (const float*)d_in[15];
  const float* W_gate  = (const float*)d_in[16];

  float* out    = (float*)d_out;
  float* o_outs = out;                 // (B,T,D)   524288
  float* o_Ks   = out + 524288;        // (B,M,D)  1048576
  float* o_Vs   = out + 1572864;       // (B,M,D)  1048576
  float* o_zK   = out + 2621440;       // (B,M)       2048
  float* o_zV   = out + 2623488;       // (B,M)       2048
  float* o_widx = out + 2625536;       // (B,8)         64
  float* o_ridx = out + 2625600;       // (B,8)         64

  float* ws    = (float*)d_ws;
  float* khat  = ws;                          // 2 * BT * D
  float* kvk   = ws + 2*(size_t)BT_*D_;       // 2 * BT * D
  float* kvv   = kvk + 2*(size_t)BT_*D_;      // 2 * BT * D
  float* rdo   = kvv + 2*(size_t)BT_*D_;      // BT * D
  float* metab = rdo + (size_t)BT_*D_;        // BT * 8 * 4
  float* pre2  = metab + (size_t)BT_*TOPK_*4; // BT * 8
  float2* zrb  = (float2*)(pre2 + (size_t)BT_*8); // BT * 8 float2

  (void)hipMemcpyAsync(o_Ks, K_slots, sizeof(float)*(size_t)B_*M_*D_,
                       hipMemcpyDeviceToDevice, stream);
  (void)hipMemcpyAsync(o_Vs, V_slots, sizeof(float)*(size_t)B_*M_*D_,
                       hipMemcpyDeviceToDevice, stream);

  addr_kernel<<<BT_, 64, 0, stream>>>(h, W_k, W_q, ltw, ltr, gamma, metab);
  zscan_kernel<<<B_, 256, 0, stream>>>(z_K, z_V, metab, zrb, o_zK, o_zV);

  GemmPtrs p{};
  p.W[0] = hh_k;           p.C[0] = khat;
  p.W[1] = hh_k + 262144;  p.C[1] = khat + (size_t)BT_*D_;
  p.W[2] = hh_vk;          p.C[2] = kvk;
  p.W[3] = hh_vk + 262144; p.C[3] = kvk + (size_t)BT_*D_;
  p.W[4] = hh_vv;          p.C[4] = kvv;
  p.W[5] = hh_vv + 262144; p.C[5] = kvv + (size_t)BT_*D_;
  gemm_nt<<<dim3(8,16,6), 256, 0, stream>>>(h, p);

  ew2_kernel<<<BT_, 256, 0, stream>>>(khat, kvk, kvv, pre2, h, hh_bw, hh_bb);

  scan_kernel<<<B_, 512, 0, stream>>>(o_Ks, o_Vs, khat, kvk, kvv,
                                      pre2, metab, zrb, h, rdo,
                                      o_widx, o_ridx);

  gemm_out<<<dim3(8,16), 256, 0, stream>>>(h, rdo, W_gate, W_out, o_outs);
}

// Round 8
// 533.724 us; speedup vs baseline: 1.0148x; 1.0148x over previous
//
#include <hip/hip_runtime.h>
#include <math.h>

#define D_ 512
#define M_ 256
#define T_ 128
#define B_ 8
#define TOPK_ 8
#define NH_ 2
#define BT_ (B_*T_)

__device__ __forceinline__ float wred(float v){
#pragma unroll
  for (int m = 1; m < 64; m <<= 1) v += __shfl_xor(v, m, 64);
  return v;
}
__device__ __forceinline__ float4 ld4(const float* p){ return *(const float4*)p; }
__device__ __forceinline__ void st4(float* p, float4 v){ *(float4*)p = v; }
__device__ __forceinline__ float dot4(float4 a, float4 b){
  return a.x*b.x + a.y*b.y + a.z*b.z + a.w*b.w;
}
__device__ __forceinline__ float4 scl4(float4 a, float s){
  a.x*=s; a.y*=s; a.z*=s; a.w*=s; return a;
}

// DPP wave64 sum (VALU-pipe only, no DS traffic).
template<int CTRL>
__device__ __forceinline__ float dpp_add(float x){
  int y = __builtin_amdgcn_update_dpp(0, __float_as_int(x), CTRL, 0xf, 0xf, true);
  return x + __int_as_float(y);
}
__device__ __forceinline__ float wredd(float x){
  x = dpp_add<0x111>(x);   // row_shr:1
  x = dpp_add<0x112>(x);   // row_shr:2
  x = dpp_add<0x114>(x);   // row_shr:4
  x = dpp_add<0x118>(x);   // row_shr:8
  x = dpp_add<0x142>(x);   // row_bcast:15
  x = dpp_add<0x143>(x);   // row_bcast:31
  return __int_as_float(__builtin_amdgcn_readlane(__float_as_int(x), 63));
}

// ---------------------------------------------------------------------------
// A1: addresses + parallel top-8. meta[bt][r] = {widx, ww, dec, ridx}.
// ---------------------------------------------------------------------------
__global__ __launch_bounds__(64) void addr_kernel(
    const float* __restrict__ h, const float* __restrict__ Wk,
    const float* __restrict__ Wq, const float* __restrict__ ltw,
    const float* __restrict__ ltr, const float* __restrict__ gammap,
    float* __restrict__ metab)
{
  const int bt = blockIdx.x;
  const int tid = threadIdx.x;
  __shared__ float p_s[64];

  const float* hrow = h + (size_t)bt*D_;
  const float* wrow = (tid < 32) ? (Wk + (size_t)tid*D_)
                                 : (Wq + (size_t)(tid-32)*D_);
  float dot = 0.f;
  for (int d = 0; d < D_; d += 4){
    float4 hv = ld4(&hrow[d]); float4 wv = ld4(&wrow[d]);
    dot += hv.x*wv.x + hv.y*wv.y + hv.z*wv.z + hv.w*wv.w;
  }
  float tau = (tid < 32) ? expf(ltw[0]) : expf(ltr[0]);
  float mx = dot;
#pragma unroll
  for (int m = 1; m < 16; m <<= 1) mx = fmaxf(mx, __shfl_xor(mx, m, 64));
  float e = expf((dot - mx)/tau);
  float sm = e;
#pragma unroll
  for (int m = 1; m < 16; m <<= 1) sm += __shfl_xor(sm, m, 64);
  p_s[tid] = e / sm;
  __syncthreads();

  const int half = tid >> 5;
  const int l = tid & 31;
  const int g0 = half*32, g1 = half*32 + 16;
  float av[8];
#pragma unroll
  for (int k = 0; k < 8; ++k){
    int x = l*8 + k;
    av[k] = p_s[g0 + (x>>4)] * p_s[g1 + (x&15)];
  }
  const float sp = log1pf(expf(gammap[0]));
  for (int r = 0; r < TOPK_; ++r){
    float bv = -1.f; int bi = 0;
#pragma unroll
    for (int k = 0; k < 8; ++k){ if (av[k] > bv){ bv = av[k]; bi = l*8+k; } }
#pragma unroll
    for (int m = 1; m < 32; m <<= 1){
      float ov = __shfl_xor(bv, m, 64); int oi = __shfl_xor(bi, m, 64);
      if (ov > bv || (ov == bv && oi < bi)){ bv = ov; bi = oi; }
    }
    if ((bi >> 3) == l) av[bi & 7] = -2.f;
    float* mp = metab + (size_t)(bt*TOPK_ + r)*4;
    if (tid == 0){
      mp[0] = __int_as_float(bi); mp[1] = bv; mp[2] = powf(1.f - bv, sp);
    }
    if (tid == 32) mp[3] = __int_as_float(bi);
  }
}

// ---------------------------------------------------------------------------
// A1b: z recurrence precompute. Thread m owns zK[m],zV[m]. Meta read via
// wave-uniform GLOBAL loads (scalar cache) — no LDS broadcast traffic.
// ---------------------------------------------------------------------------
__global__ __launch_bounds__(256) void zscan_kernel(
    const float* __restrict__ zK0, const float* __restrict__ zV0,
    const float* __restrict__ metab, float2* __restrict__ zr,
    float* __restrict__ o_zK, float* __restrict__ o_zV)
{
  const int b = blockIdx.x;
  const int m = threadIdx.x;
  const float4* mb = (const float4*)metab + (size_t)b*T_*TOPK_;
  float zk = zK0[b*M_+m], zv = zV0[b*M_+m];
  for (int t = 0; t < T_; ++t){
    float4 me[TOPK_];
#pragma unroll
    for (int i = 0; i < TOPK_; ++i) me[i] = mb[t*TOPK_+i];  // uniform -> s_load
#pragma unroll
    for (int i = 0; i < TOPK_; ++i){
      if (m == __float_as_int(me[i].x)){
        zk = me[i].z*zk + me[i].y; zv = me[i].z*zv + me[i].y;
      }
    }
#pragma unroll
    for (int i = 0; i < TOPK_; ++i){
      if (m == __float_as_int(me[i].w))
        zr[(size_t)(b*T_+t)*TOPK_+i] = make_float2(1.f/zk, 1.f/zv);
    }
  }
  o_zK[b*M_+m] = zk; o_zV[b*M_+m] = zv;
}

// ---------------------------------------------------------------------------
// A2: fp32 NT GEMM, 64x64 tile, double-buffered LDS, ONE sync per K-iter.
// ---------------------------------------------------------------------------
struct GemmPtrs { const float* W[6]; float* C[6]; };

__global__ __launch_bounds__(256) void gemm_nt(
    const float* __restrict__ A, GemmPtrs p)
{
  const float* W = p.W[blockIdx.z];
  float* C = p.C[blockIdx.z];
  const int n0 = blockIdx.x * 64;
  const int m0 = blockIdx.y * 64;
  const int tid = threadIdx.x;
  __shared__ __align__(16) float As[2][16][68];
  __shared__ __align__(16) float Bs[2][16][68];
  const int r  = tid >> 2;
  const int c4 = (tid & 3) << 2;
  const int tx4 = (tid & 15) << 2;
  const int ty4 = (tid >> 4) << 2;
  float acc[4][4] = {{0.f}};

  {
    float4 av = ld4(&A[(size_t)(m0+r)*512 + c4]);
    float4 wv = ld4(&W[(size_t)(n0+r)*512 + c4]);
    As[0][c4+0][r]=av.x; As[0][c4+1][r]=av.y; As[0][c4+2][r]=av.z; As[0][c4+3][r]=av.w;
    Bs[0][c4+0][r]=wv.x; Bs[0][c4+1][r]=wv.y; Bs[0][c4+2][r]=wv.z; Bs[0][c4+3][r]=wv.w;
  }
  __syncthreads();

  for (int kc = 0, buf = 0; kc < 512; kc += 16, buf ^= 1){
    float4 av, wv;
    const bool more = (kc + 16 < 512);
    if (more){
      av = ld4(&A[(size_t)(m0+r)*512 + kc + 16 + c4]);
      wv = ld4(&W[(size_t)(n0+r)*512 + kc + 16 + c4]);
    }
#pragma unroll
    for (int k = 0; k < 16; ++k){
      float4 a  = ld4(&As[buf][k][ty4]);
      float4 bq = ld4(&Bs[buf][k][tx4]);
      acc[0][0]+=a.x*bq.x; acc[0][1]+=a.x*bq.y; acc[0][2]+=a.x*bq.z; acc[0][3]+=a.x*bq.w;
      acc[1][0]+=a.y*bq.x; acc[1][1]+=a.y*bq.y; acc[1][2]+=a.y*bq.z; acc[1][3]+=a.y*bq.w;
      acc[2][0]+=a.z*bq.x; acc[2][1]+=a.z*bq.y; acc[2][2]+=a.z*bq.z; acc[2][3]+=a.z*bq.w;
      acc[3][0]+=a.w*bq.x; acc[3][1]+=a.w*bq.y; acc[3][2]+=a.w*bq.z; acc[3][3]+=a.w*bq.w;
    }
    if (more){
      int nb = buf ^ 1;
      As[nb][c4+0][r]=av.x; As[nb][c4+1][r]=av.y; As[nb][c4+2][r]=av.z; As[nb][c4+3][r]=av.w;
      Bs[nb][c4+0][r]=wv.x; Bs[nb][c4+1][r]=wv.y; Bs[nb][c4+2][r]=wv.z; Bs[nb][c4+3][r]=wv.w;
      __syncthreads();
    }
  }
#pragma unroll
  for (int i = 0; i < 4; ++i){
    float4 cv; cv.x=acc[i][0]; cv.y=acc[i][1]; cv.z=acc[i][2]; cv.w=acc[i][3];
    st4(&C[(size_t)(m0+ty4+i)*512 + n0 + tx4], cv);
  }
}

// ---------------------------------------------------------------------------
// C: fused out = sigmoid(h@Wg.T) * (rdo@Wo.T).
// ---------------------------------------------------------------------------
__global__ __launch_bounds__(256) void gemm_out(
    const float* __restrict__ h, const float* __restrict__ rdo,
    const float* __restrict__ Wg, const float* __restrict__ Wo,
    float* __restrict__ C)
{
  const int n0 = blockIdx.x * 64;
  const int m0 = blockIdx.y * 64;
  const int tid = threadIdx.x;
  __shared__ __align__(16) float Ag[16][68];
  __shared__ __align__(16) float Ao[16][68];
  __shared__ __align__(16) float Bg[16][68];
  __shared__ __align__(16) float Bo[16][68];
  const int r  = tid >> 2;
  const int c4 = (tid & 3) << 2;
  const int tx4 = (tid & 15) << 2;
  const int ty4 = (tid >> 4) << 2;
  float accg[4][4] = {{0.f}};
  float acco[4][4] = {{0.f}};

  for (int kc = 0; kc < 512; kc += 16){
    float4 a1 = ld4(&h  [(size_t)(m0+r)*512 + kc + c4]);
    float4 a2 = ld4(&rdo[(size_t)(m0+r)*512 + kc + c4]);
    float4 w1 = ld4(&Wg [(size_t)(n0+r)*512 + kc + c4]);
    float4 w2 = ld4(&Wo [(size_t)(n0+r)*512 + kc + c4]);
    __syncthreads();
    Ag[c4+0][r]=a1.x; Ag[c4+1][r]=a1.y; Ag[c4+2][r]=a1.z; Ag[c4+3][r]=a1.w;
    Ao[c4+0][r]=a2.x; Ao[c4+1][r]=a2.y; Ao[c4+2][r]=a2.z; Ao[c4+3][r]=a2.w;
    Bg[c4+0][r]=w1.x; Bg[c4+1][r]=w1.y; Bg[c4+2][r]=w1.z; Bg[c4+3][r]=w1.w;
    Bo[c4+0][r]=w2.x; Bo[c4+1][r]=w2.y; Bo[c4+2][r]=w2.z; Bo[c4+3][r]=w2.w;
    __syncthreads();
#pragma unroll
    for (int k = 0; k < 16; ++k){
      float4 ag = ld4(&Ag[k][ty4]);
      float4 ao = ld4(&Ao[k][ty4]);
      float4 bg = ld4(&Bg[k][tx4]);
      float4 bo = ld4(&Bo[k][tx4]);
      accg[0][0]+=ag.x*bg.x; accg[0][1]+=ag.x*bg.y; accg[0][2]+=ag.x*bg.z; accg[0][3]+=ag.x*bg.w;
      accg[1][0]+=ag.y*bg.x; accg[1][1]+=ag.y*bg.y; accg[1][2]+=ag.y*bg.z; accg[1][3]+=ag.y*bg.w;
      accg[2][0]+=ag.z*bg.x; accg[2][1]+=ag.z*bg.y; accg[2][2]+=ag.z*bg.z; accg[2][3]+=ag.z*bg.w;
      accg[3][0]+=ag.w*bg.x; accg[3][1]+=ag.w*bg.y; accg[3][2]+=ag.w*bg.z; accg[3][3]+=ag.w*bg.w;
      acco[0][0]+=ao.x*bo.x; acco[0][1]+=ao.x*bo.y; acco[0][2]+=ao.x*bo.z; acco[0][3]+=ao.x*bo.w;
      acco[1][0]+=ao.y*bo.x; acco[1][1]+=ao.y*bo.y; acco[1][2]+=ao.y*bo.z; acco[1][3]+=ao.y*bo.w;
      acco[2][0]+=ao.z*bo.x; acco[2][1]+=ao.z*bo.y; acco[2][2]+=ao.z*bo.z; acco[2][3]+=ao.z*bo.w;
      acco[3][0]+=ao.w*bo.x; acco[3][1]+=ao.w*bo.y; acco[3][2]+=ao.w*bo.z; acco[3][3]+=ao.w*bo.w;
    }
  }
#pragma unroll
  for (int i = 0; i < 4; ++i){
    float4 cv;
    cv.x = acco[i][0] / (1.f + expf(-accg[i][0]));
    cv.y = acco[i][1] / (1.f + expf(-accg[i][1]));
    cv.z = acco[i][2] / (1.f + expf(-accg[i][2]));
    cv.w = acco[i][3] / (1.f + expf(-accg[i][3]));
    st4(&C[(size_t)(m0+ty4+i)*512 + n0 + tx4], cv);
  }
}

// ---------------------------------------------------------------------------
// A3: fused per-bt elementwise + cross-head precompute.
// ---------------------------------------------------------------------------
__global__ __launch_bounds__(256) void ew2_kernel(
    float* __restrict__ khat, float* __restrict__ kvk, float* __restrict__ kvv,
    float* __restrict__ pre2, const float* __restrict__ h,
    const float* __restrict__ hh_bw, const float* __restrict__ hh_bb)
{
  const int bt = blockIdx.x;
  const int tid = threadIdx.x;
  const int wid = tid >> 6, lane = tid & 63;
  float* k0p  = khat + (size_t)bt*D_;
  float* k1p  = khat + (size_t)BT_*D_ + (size_t)bt*D_;
  float* vk0p = kvk  + (size_t)bt*D_;
  float* vk1p = kvk  + (size_t)BT_*D_ + (size_t)bt*D_;
  float* vv0p = kvv  + (size_t)bt*D_;
  float* vv1p = kvv  + (size_t)BT_*D_ + (size_t)bt*D_;
  const float* hp  = h + (size_t)bt*D_;

  float s0[2], s1[2];
  float n0 = 0.f, n1 = 0.f, bd0 = 0.f, bd1 = 0.f;
#pragma unroll
  for (int q = 0; q < 2; ++q){
    int d = tid + q*256;
    float x0 = k0p[d], x1 = k1p[d], hv = hp[d];
    float v0 = x0 / (1.f + expf(-x0));
    float v1 = x1 / (1.f + expf(-x1));
    s0[q] = v0; s1[q] = v1;
    n0 += v0*v0; n1 += v1*v1;
    bd0 += hv*hh_bw[d]; bd1 += hv*hh_bw[D_ + d];
  }
  __shared__ float4 rb[4];
  float4 acc = make_float4(wred(n0), wred(n1), wred(bd0), wred(bd1));
  if (lane == 0) rb[wid] = acc;
  __syncthreads();
  float4 t0 = rb[0], t1 = rb[1], t2 = rb[2], t3 = rb[3];
  n0 = t0.x+t1.x+t2.x+t3.x; n1 = t0.y+t1.y+t2.y+t3.y;
  bd0 = t0.z+t1.z+t2.z+t3.z; bd1 = t0.w+t1.w+t2.w+t3.w;
  float inv0 = 1.f / fmaxf(sqrtf(n0), 1e-12f);
  float inv1 = 1.f / fmaxf(sqrtf(n1), 1e-12f);
  float be0 = 2.f / (1.f + expf(-(bd0 + hh_bb[0])));
  float be1 = 2.f / (1.f + expf(-(bd1 + hh_bb[1])));

  float c01 = 0.f, dK = 0.f, dV = 0.f;
#pragma unroll
  for (int q = 0; q < 2; ++q){
    int d = tid + q*256;
    float kh0 = s0[q]*inv0, kh1 = s1[q]*inv1;
    float u0K = s0[q]*vk0p[d], u1K = s1[q]*vk1p[d];
    float u0V = s0[q]*vv0p[d], u1V = s1[q]*vv1p[d];
    k0p[d] = kh0; k1p[d] = kh1;
    vk0p[d] = be0*u0K + be1*u1K;
    vv0p[d] = be0*u0V + be1*u1V;
    c01 += kh1*kh0; dK += kh1*u0K; dV += kh1*u0V;
  }
  __syncthreads();
  float4 acc2 = make_float4(wred(c01), wred(dK), wred(dV), 0.f);
  if (lane == 0) rb[wid] = acc2;
  __syncthreads();
  if (tid == 0){
    float4 a = rb[0], b = rb[1], c = rb[2], d = rb[3];
    pre2[(size_t)bt*8+0] = a.x+b.x+c.x+d.x;
    pre2[(size_t)bt*8+1] = a.y+b.y+c.y+d.y;
    pre2[(size_t)bt*8+2] = a.z+b.z+c.z+d.z;
    pre2[(size_t)bt*8+3] = be0;
    pre2[(size_t)bt*8+4] = be1;
  }
}

// ---------------------------------------------------------------------------
// B: sequential scan v7 — one barrier/step; staged vectors in REGISTERS
// prefetched from global (L2 broadcast on the idle VMEM pipe), no LDS ring.
// ---------------------------------------------------------------------------
__global__ __launch_bounds__(512) void scan_kernel(
    float* __restrict__ Ks, float* __restrict__ Vs,
    const float* __restrict__ khat, const float* __restrict__ ucKp,
    const float* __restrict__ ucVp, const float* __restrict__ pre2,
    const float* __restrict__ metab, const float2* __restrict__ zr,
    const float* __restrict__ h, float* __restrict__ readout,
    float* __restrict__ o_widx, float* __restrict__ o_ridx)
{
  __shared__ __align__(16) float Vr_s[2][TOPK_][D_];
  __shared__ float2 rel2_s[2][TOPK_];

  const int b = blockIdx.x;
  const int tid = threadIdx.x;
  const int s = tid >> 6, lane = tid & 63;
  const int l4 = lane * 4;
  const float scale = 0.044194173824159216f;   // 1/sqrt(512)

  float* Ksb = Ks + (size_t)b*M_*D_;
  float* Vsb = Vs + (size_t)b*M_*D_;
  const float* kh0p = khat;
  const float* kh1p = khat + (size_t)BT_*D_;
  const float4* mb = (const float4*)metab;

  // ---- prologue: staged(0), meta(0..1), state rows(0) ----
  const int bt0 = b*T_;
  size_t o0 = (size_t)bt0*D_ + l4;
  float4 c_kh0a = ld4(kh0p+o0), c_kh0b = ld4(kh0p+o0+256);
  float4 c_kh1a = ld4(kh1p+o0), c_kh1b = ld4(kh1p+o0+256);
  float4 c_uKa  = ld4(ucKp+o0), c_uKb  = ld4(ucKp+o0+256);
  float4 c_uVa  = ld4(ucVp+o0), c_uVb  = ld4(ucVp+o0+256);

  float4 me   = mb[bt0*TOPK_ + s];
  float4 me_n = mb[(bt0+1)*TOPK_ + s];
  float4 pm   = ld4(&pre2[(size_t)bt0*8]);
  float  be1v = pre2[(size_t)bt0*8+4];
  float4 pm_n = ld4(&pre2[(size_t)(bt0+1)*8]);
  float  be1_n= pre2[(size_t)(bt0+1)*8+4];
  float2 zr2   = zr[(size_t)bt0*TOPK_ + s];
  float2 zr2_n = zr[(size_t)(bt0+1)*TOPK_ + s];

  int mi = __float_as_int(me.x);
  float4 K0 = ld4(&Ksb[(size_t)mi*D_ + l4]);
  float4 K1 = ld4(&Ksb[(size_t)mi*D_ + 256 + l4]);
  float4 V0 = ld4(&Vsb[(size_t)mi*D_ + l4]);
  float4 V1 = ld4(&Vsb[(size_t)mi*D_ + 256 + l4]);

#pragma unroll 2
  for (int t = 0; t < T_; ++t){
    const int bt = b*T_ + t;
    const float dec = me.z;
    const int   ri  = __float_as_int(me.w);
    mi = __float_as_int(me.x);

    // ---------------- A(t) ----------------
    // issue staged(t+1) prefetch (registers; ~700 cyc to the barrier drain)
    const int btn = (t+1 < T_) ? bt+1 : bt;
    size_t on = (size_t)btn*D_ + l4;
    float4 n_kh0a = ld4(kh0p+on), n_kh0b = ld4(kh0p+on+256);
    float4 n_kh1a = ld4(kh1p+on), n_kh1b = ld4(kh1p+on+256);
    float4 n_uKa  = ld4(ucKp+on), n_uKb  = ld4(ucKp+on+256);
    float4 n_uVa  = ld4(ucVp+on), n_uVb  = ld4(ucVp+on+256);
    float4 HTa = ld4(h + (size_t)bt*D_ + l4);      // for B's read-dot
    float4 HTb = ld4(h + (size_t)bt*D_ + 256 + l4);

    // fused 2-head state update (staged regs resident since A(t-1))
    K0 = scl4(K0,dec); K1 = scl4(K1,dec);
    V0 = scl4(V0,dec); V1 = scl4(V1,dec);
    float aK = wredd(dot4(K0,c_kh0a) + dot4(K1,c_kh0b));
    float bK = wredd(dot4(K0,c_kh1a) + dot4(K1,c_kh1b));
    float aV = wredd(dot4(V0,c_kh0a) + dot4(V1,c_kh0b));
    float bV = wredd(dot4(V0,c_kh1a) + dot4(V1,c_kh1b));
    float p0K = pm.w*aK, p1K = be1v*(bK + pm.w*(pm.y - aK*pm.x));
    float p0V = pm.w*aV, p1V = be1v*(bV + pm.w*(pm.z - aV*pm.x));
    K0.x += c_uKa.x - p0K*c_kh0a.x - p1K*c_kh1a.x;
    K0.y += c_uKa.y - p0K*c_kh0a.y - p1K*c_kh1a.y;
    K0.z += c_uKa.z - p0K*c_kh0a.z - p1K*c_kh1a.z;
    K0.w += c_uKa.w - p0K*c_kh0a.w - p1K*c_kh1a.w;
    K1.x += c_uKb.x - p0K*c_kh0b.x - p1K*c_kh1b.x;
    K1.y += c_uKb.y - p0K*c_kh0b.y - p1K*c_kh1b.y;
    K1.z += c_uKb.z - p0K*c_kh0b.z - p1K*c_kh1b.z;
    K1.w += c_uKb.w - p0K*c_kh0b.w - p1K*c_kh1b.w;
    V0.x += c_uVa.x - p0V*c_kh0a.x - p1V*c_kh1a.x;
    V0.y += c_uVa.y - p0V*c_kh0a.y - p1V*c_kh1a.y;
    V0.z += c_uVa.z - p0V*c_kh0a.z - p1V*c_kh1a.z;
    V0.w += c_uVa.w - p0V*c_kh0a.w - p1V*c_kh1a.w;
    V1.x += c_uVb.x - p0V*c_kh0b.x - p1V*c_kh1b.x;
    V1.y += c_uVb.y - p0V*c_kh0b.y - p1V*c_kh1b.y;
    V1.z += c_uVb.z - p0V*c_kh0b.z - p1V*c_kh1b.z;
    V1.w += c_uVb.w - p0V*c_kh0b.w - p1V*c_kh1b.w;

    st4(&Ksb[(size_t)mi*D_ + l4], K0); st4(&Ksb[(size_t)mi*D_ + 256 + l4], K1);
    st4(&Vsb[(size_t)mi*D_ + l4], V0); st4(&Vsb[(size_t)mi*D_ + 256 + l4], V1);

    __syncthreads();   // THE barrier: scatters drained & visible

    // ---------------- B(t) ----------------
    float4 RK0 = ld4(&Ksb[(size_t)ri*D_ + l4]);
    float4 RK1 = ld4(&Ksb[(size_t)ri*D_ + 256 + l4]);
    float4 RV0 = ld4(&Vsb[(size_t)ri*D_ + l4]);
    float4 RV1 = ld4(&Vsb[(size_t)ri*D_ + 256 + l4]);
    const int mi_n = __float_as_int(me_n.x);
    float4 nK0 = ld4(&Ksb[(size_t)mi_n*D_ + l4]);
    float4 nK1 = ld4(&Ksb[(size_t)mi_n*D_ + 256 + l4]);
    float4 nV0 = ld4(&Vsb[(size_t)mi_n*D_ + l4]);
    float4 nV1 = ld4(&Vsb[(size_t)mi_n*D_ + 256 + l4]);
    const int btnn = (t+2 < T_) ? bt+2 : b*T_+T_-1;
    float4 me_nn = mb[btnn*TOPK_ + s];
    float4 pm_nn = ld4(&pre2[(size_t)btnn*8]);
    float  be1nn = pre2[(size_t)btnn*8+4];
    float2 zr2nn = zr[(size_t)btnn*TOPK_ + s];

    // readout(t-1): overlaps the loads above
    if (t > 0){
      const int pp = (t-1) & 1;
      float2 rz[TOPK_];
#pragma unroll
      for (int i = 0; i < TOPK_; ++i) rz[i] = rel2_s[pp][i];
      float mx = rz[0].x;
#pragma unroll
      for (int i = 1; i < TOPK_; ++i) mx = fmaxf(mx, rz[i].x);
      float smm = 0.f, r = 0.f;
#pragma unroll
      for (int i = 0; i < TOPK_; ++i){
        float ev = __expf(rz[i].x - mx); smm += ev;
        r += ev * rz[i].y * Vr_s[pp][i][tid];
      }
      readout[(size_t)(bt-1)*D_ + tid] = r * __builtin_amdgcn_rcpf(smm);
    }

    // resolve(t)
    float dt = wredd(dot4(RK0,HTa) + dot4(RK1,HTb));
    if (lane == 0)
      rel2_s[t&1][s] = make_float2(dt * scale * zr2.x, zr2.y);
    st4(&Vr_s[t&1][s][l4], RV0); st4(&Vr_s[t&1][s][256+l4], RV1);

    // rotate pipeline (register renaming under unroll)
    K0=nK0; K1=nK1; V0=nV0; V1=nV1;
    me=me_n; pm=pm_n; be1v=be1_n; zr2=zr2_n;
    me_n=me_nn; pm_n=pm_nn; be1_n=be1nn; zr2_n=zr2nn;
    c_kh0a=n_kh0a; c_kh0b=n_kh0b; c_kh1a=n_kh1a; c_kh1b=n_kh1b;
    c_uKa=n_uKa; c_uKb=n_uKb; c_uVa=n_uVa; c_uVb=n_uVb;
  }

  // ---- epilogue: readout(T-1) ----
  __syncthreads();
  {
    const int btL = b*T_ + T_ - 1;
    const int pp = (T_-1) & 1;
    float2 rz[TOPK_];
#pragma unroll
    for (int i = 0; i < TOPK_; ++i) rz[i] = rel2_s[pp][i];
    float mx = rz[0].x;
#pragma unroll
    for (int i = 1; i < TOPK_; ++i) mx = fmaxf(mx, rz[i].x);
    float smm = 0.f, r = 0.f;
#pragma unroll
    for (int i = 0; i < TOPK_; ++i){
      float ev = __expf(rz[i].x - mx); smm += ev;
      r += ev * rz[i].y * Vr_s[pp][i][tid];
    }
    readout[(size_t)btL*D_ + tid] = r * __builtin_amdgcn_rcpf(smm);

    if (tid < TOPK_){
      float4 m = mb[btL*TOPK_ + tid];
      o_widx[b*TOPK_+tid] = (float)__float_as_int(m.x);
      o_ridx[b*TOPK_+tid] = (float)__float_as_int(m.w);
    }
  }
}

// ---------------------------------------------------------------------------
extern "C" void kernel_launch(void* const* d_in, const int* in_sizes, int n_in,
                              void* d_out, int out_size, void* d_ws, size_t ws_size,
                              hipStream_t stream)
{
  (void)in_sizes; (void)n_in; (void)out_size; (void)ws_size;
  const float* h       = (const float*)d_in[0];
  const float* K_slots = (const float*)d_in[1];
  const float* V_slots = (const float*)d_in[2];
  const float* z_K     = (const float*)d_in[3];
  const float* z_V     = (const float*)d_in[4];
  const float* W_k     = (const float*)d_in[5];
  const float* W_q     = (const float*)d_in[6];
  const float* ltw     = (const float*)d_in[7];
  const float* ltr     = (const float*)d_in[8];
  const float* hh_k    = (const float*)d_in[9];
  const float* hh_vk   = (const float*)d_in[10];
  const float* hh_vv   = (const float*)d_in[11];
  const float* hh_bw   = (const float*)d_in[12];
  const float* hh_bb   = (const float*)d_in[13];
  const float* gamma   = (const float*)d_in[14];
  const float* W_out   = (const float*)d_in[15];
  const float* W_gate  = (const float*)d_in[16];

  float* out    = (float*)d_out;
  float* o_outs = out;                 // (B,T,D)   524288
  float* o_Ks   = out + 524288;        // (B,M,D)  1048576
  float* o_Vs   = out + 1572864;       // (B,M,D)  1048576
  float* o_zK   = out + 2621440;       // (B,M)       2048
  float* o_zV   = out + 2623488;       // (B,M)       2048
  float* o_widx = out + 2625536;       // (B,8)         64
  float* o_ridx = out + 2625600;       // (B,8)         64

  float* ws    = (float*)d_ws;
  float* khat  = ws;                          // 2 * BT * D
  float* kvk   = ws + 2*(size_t)BT_*D_;       // 2 * BT * D
  float* kvv   = kvk + 2*(size_t)BT_*D_;      // 2 * BT * D
  float* rdo   = kvv + 2*(size_t)BT_*D_;      // BT * D
  float* metab = rdo + (size_t)BT_*D_;        // BT * 8 * 4
  float* pre2  = metab + (size_t)BT_*TOPK_*4; // BT * 8
  float2* zrb  = (float2*)(pre2 + (size_t)BT_*8); // BT * 8 float2

  (void)hipMemcpyAsync(o_Ks, K_slots, sizeof(float)*(size_t)B_*M_*D_,
                       hipMemcpyDeviceToDevice, stream);
  (void)hipMemcpyAsync(o_Vs, V_slots, sizeof(float)*(size_t)B_*M_*D_,
                       hipMemcpyDeviceToDevice, stream);

  addr_kernel<<<BT_, 64, 0, stream>>>(h, W_k, W_q, ltw, ltr, gamma, metab);
  zscan_kernel<<<B_, 256, 0, stream>>>(z_K, z_V, metab, zrb, o_zK, o_zV);

  GemmPtrs p{};
  p.W[0] = hh_k;           p.C[0] = khat;
  p.W[1] = hh_k + 262144;  p.C[1] = khat + (size_t)BT_*D_;
  p.W[2] = hh_vk;          p.C[2] = kvk;
  p.W[3] = hh_vk + 262144; p.C[3] = kvk + (size_t)BT_*D_;
  p.W[4] = hh_vv;          p.C[4] = kvv;
  p.W[5] = hh_vv + 262144; p.C[5] = kvv + (size_t)BT_*D_;
  gemm_nt<<<dim3(8,16,6), 256, 0, stream>>>(h, p);

  ew2_kernel<<<BT_, 256, 0, stream>>>(khat, kvk, kvv, pre2, h, hh_bw, hh_bb);

  scan_kernel<<<B_, 512, 0, stream>>>(o_Ks, o_Vs, khat, kvk, kvv,
                                      pre2, metab, zrb, h, rdo,
                                      o_widx, o_ridx);

  gemm_out<<<dim3(8,16), 256, 0, stream>>>(h, rdo, W_gate, W_out, o_outs);
}

// Round 9
// 464.136 us; speedup vs baseline: 1.1669x; 1.1499x over previous
//
#include <hip/hip_runtime.h>
#include <math.h>

#define D_ 512
#define M_ 256
#define T_ 128
#define B_ 8
#define TOPK_ 8
#define NH_ 2
#define BT_ (B_*T_)

__device__ __forceinline__ float wred(float v){
#pragma unroll
  for (int m = 1; m < 64; m <<= 1) v += __shfl_xor(v, m, 64);
  return v;
}
__device__ __forceinline__ float4 ld4(const float* p){ return *(const float4*)p; }
__device__ __forceinline__ void st4(float* p, float4 v){ *(float4*)p = v; }
__device__ __forceinline__ float dot4(float4 a, float4 b){
  return a.x*b.x + a.y*b.y + a.z*b.z + a.w*b.w;
}
__device__ __forceinline__ float4 scl4(float4 a, float s){
  a.x*=s; a.y*=s; a.z*=s; a.w*=s; return a;
}

// DPP wave64 sum (VALU-pipe only, no DS traffic).
template<int CTRL>
__device__ __forceinline__ float dpp_add(float x){
  int y = __builtin_amdgcn_update_dpp(0, __float_as_int(x), CTRL, 0xf, 0xf, true);
  return x + __int_as_float(y);
}
__device__ __forceinline__ float wredd(float x){
  x = dpp_add<0x111>(x);   // row_shr:1
  x = dpp_add<0x112>(x);   // row_shr:2
  x = dpp_add<0x114>(x);   // row_shr:4
  x = dpp_add<0x118>(x);   // row_shr:8
  x = dpp_add<0x142>(x);   // row_bcast:15
  x = dpp_add<0x143>(x);   // row_bcast:31
  return __int_as_float(__builtin_amdgcn_readlane(__float_as_int(x), 63));
}

// ---------------------------------------------------------------------------
// A1: addresses + parallel top-8. meta[bt][r] = {widx, ww, dec, ridx}.
// ---------------------------------------------------------------------------
__global__ __launch_bounds__(64) void addr_kernel(
    const float* __restrict__ h, const float* __restrict__ Wk,
    const float* __restrict__ Wq, const float* __restrict__ ltw,
    const float* __restrict__ ltr, const float* __restrict__ gammap,
    float* __restrict__ metab)
{
  const int bt = blockIdx.x;
  const int tid = threadIdx.x;
  __shared__ float p_s[64];

  const float* hrow = h + (size_t)bt*D_;
  const float* wrow = (tid < 32) ? (Wk + (size_t)tid*D_)
                                 : (Wq + (size_t)(tid-32)*D_);
  float dot = 0.f;
  for (int d = 0; d < D_; d += 4){
    float4 hv = ld4(&hrow[d]); float4 wv = ld4(&wrow[d]);
    dot += hv.x*wv.x + hv.y*wv.y + hv.z*wv.z + hv.w*wv.w;
  }
  float tau = (tid < 32) ? expf(ltw[0]) : expf(ltr[0]);
  float mx = dot;
#pragma unroll
  for (int m = 1; m < 16; m <<= 1) mx = fmaxf(mx, __shfl_xor(mx, m, 64));
  float e = expf((dot - mx)/tau);
  float sm = e;
#pragma unroll
  for (int m = 1; m < 16; m <<= 1) sm += __shfl_xor(sm, m, 64);
  p_s[tid] = e / sm;
  __syncthreads();

  const int half = tid >> 5;
  const int l = tid & 31;
  const int g0 = half*32, g1 = half*32 + 16;
  float av[8];
#pragma unroll
  for (int k = 0; k < 8; ++k){
    int x = l*8 + k;
    av[k] = p_s[g0 + (x>>4)] * p_s[g1 + (x&15)];
  }
  const float sp = log1pf(expf(gammap[0]));
  for (int r = 0; r < TOPK_; ++r){
    float bv = -1.f; int bi = 0;
#pragma unroll
    for (int k = 0; k < 8; ++k){ if (av[k] > bv){ bv = av[k]; bi = l*8+k; } }
#pragma unroll
    for (int m = 1; m < 32; m <<= 1){
      float ov = __shfl_xor(bv, m, 64); int oi = __shfl_xor(bi, m, 64);
      if (ov > bv || (ov == bv && oi < bi)){ bv = ov; bi = oi; }
    }
    if ((bi >> 3) == l) av[bi & 7] = -2.f;
    float* mp = metab + (size_t)(bt*TOPK_ + r)*4;
    if (tid == 0){
      mp[0] = __int_as_float(bi); mp[1] = bv; mp[2] = powf(1.f - bv, sp);
    }
    if (tid == 32) mp[3] = __int_as_float(bi);
  }
}

// ---------------------------------------------------------------------------
// A2 (+A1b fused): fp32 NT GEMM, 64x64 tile, double-buffered LDS, batched
// over grid.z; grid.z==6 / blockIdx.y==0 blocks run the z-recurrence scan
// concurrently (it rides free under the GEMM's duration).
// ---------------------------------------------------------------------------
struct GemmPtrs { const float* W[6]; float* C[6]; };

__global__ __launch_bounds__(256) void gemm_nt(
    const float* __restrict__ A, GemmPtrs p,
    const float* __restrict__ zK0, const float* __restrict__ zV0,
    const float* __restrict__ metab, float2* __restrict__ zr,
    float* __restrict__ o_zK, float* __restrict__ o_zV)
{
  if (blockIdx.z == 6){
    if (blockIdx.y != 0) return;
    // ---- zscan: thread m owns zK[m], zV[m]; meta prefetched 1 step ahead --
    const int b = blockIdx.x;
    const int m = threadIdx.x;
    const float4* mb = (const float4*)metab + (size_t)b*T_*TOPK_;
    float zk = zK0[b*M_+m], zv = zV0[b*M_+m];
    float4 cur[TOPK_];
#pragma unroll
    for (int i = 0; i < TOPK_; ++i) cur[i] = mb[i];
    for (int t = 0; t < T_; ++t){
      const float4* src = mb + ((t+1 < T_) ? (t+1)*TOPK_ : t*TOPK_);
      float4 nxt[TOPK_];
#pragma unroll
      for (int i = 0; i < TOPK_; ++i) nxt[i] = src[i];
#pragma unroll
      for (int i = 0; i < TOPK_; ++i){
        bool hit = (m == __float_as_int(cur[i].x));
        float nzk = cur[i].z*zk + cur[i].y;
        float nzv = cur[i].z*zv + cur[i].y;
        zk = hit ? nzk : zk;
        zv = hit ? nzv : zv;
      }
#pragma unroll
      for (int i = 0; i < TOPK_; ++i){
        if (m == __float_as_int(cur[i].w))
          zr[(size_t)(b*T_+t)*TOPK_+i] =
              make_float2(1.0f/zk, 1.0f/zv);
      }
#pragma unroll
      for (int i = 0; i < TOPK_; ++i) cur[i] = nxt[i];
    }
    o_zK[b*M_+m] = zk; o_zV[b*M_+m] = zv;
    return;
  }

  const float* W = p.W[blockIdx.z];
  float* C = p.C[blockIdx.z];
  const int n0 = blockIdx.x * 64;
  const int m0 = blockIdx.y * 64;
  const int tid = threadIdx.x;
  __shared__ __align__(16) float As[2][16][68];
  __shared__ __align__(16) float Bs[2][16][68];
  const int r  = tid >> 2;
  const int c4 = (tid & 3) << 2;
  const int tx4 = (tid & 15) << 2;
  const int ty4 = (tid >> 4) << 2;
  float acc[4][4] = {{0.f}};

  {
    float4 av = ld4(&A[(size_t)(m0+r)*512 + c4]);
    float4 wv = ld4(&W[(size_t)(n0+r)*512 + c4]);
    As[0][c4+0][r]=av.x; As[0][c4+1][r]=av.y; As[0][c4+2][r]=av.z; As[0][c4+3][r]=av.w;
    Bs[0][c4+0][r]=wv.x; Bs[0][c4+1][r]=wv.y; Bs[0][c4+2][r]=wv.z; Bs[0][c4+3][r]=wv.w;
  }
  __syncthreads();

  for (int kc = 0, buf = 0; kc < 512; kc += 16, buf ^= 1){
    float4 av, wv;
    const bool more = (kc + 16 < 512);
    if (more){
      av = ld4(&A[(size_t)(m0+r)*512 + kc + 16 + c4]);
      wv = ld4(&W[(size_t)(n0+r)*512 + kc + 16 + c4]);
    }
#pragma unroll
    for (int k = 0; k < 16; ++k){
      float4 a  = ld4(&As[buf][k][ty4]);
      float4 bq = ld4(&Bs[buf][k][tx4]);
      acc[0][0]+=a.x*bq.x; acc[0][1]+=a.x*bq.y; acc[0][2]+=a.x*bq.z; acc[0][3]+=a.x*bq.w;
      acc[1][0]+=a.y*bq.x; acc[1][1]+=a.y*bq.y; acc[1][2]+=a.y*bq.z; acc[1][3]+=a.y*bq.w;
      acc[2][0]+=a.z*bq.x; acc[2][1]+=a.z*bq.y; acc[2][2]+=a.z*bq.z; acc[2][3]+=a.z*bq.w;
      acc[3][0]+=a.w*bq.x; acc[3][1]+=a.w*bq.y; acc[3][2]+=a.w*bq.z; acc[3][3]+=a.w*bq.w;
    }
    if (more){
      int nb = buf ^ 1;
      As[nb][c4+0][r]=av.x; As[nb][c4+1][r]=av.y; As[nb][c4+2][r]=av.z; As[nb][c4+3][r]=av.w;
      Bs[nb][c4+0][r]=wv.x; Bs[nb][c4+1][r]=wv.y; Bs[nb][c4+2][r]=wv.z; Bs[nb][c4+3][r]=wv.w;
      __syncthreads();
    }
  }
#pragma unroll
  for (int i = 0; i < 4; ++i){
    float4 cv; cv.x=acc[i][0]; cv.y=acc[i][1]; cv.z=acc[i][2]; cv.w=acc[i][3];
    st4(&C[(size_t)(m0+ty4+i)*512 + n0 + tx4], cv);
  }
}

// ---------------------------------------------------------------------------
// C: fused out = sigmoid(h@Wg.T) * (rdo@Wo.T).
// ---------------------------------------------------------------------------
__global__ __launch_bounds__(256) void gemm_out(
    const float* __restrict__ h, const float* __restrict__ rdo,
    const float* __restrict__ Wg, const float* __restrict__ Wo,
    float* __restrict__ C)
{
  const int n0 = blockIdx.x * 64;
  const int m0 = blockIdx.y * 64;
  const int tid = threadIdx.x;
  __shared__ __align__(16) float Ag[16][68];
  __shared__ __align__(16) float Ao[16][68];
  __shared__ __align__(16) float Bg[16][68];
  __shared__ __align__(16) float Bo[16][68];
  const int r  = tid >> 2;
  const int c4 = (tid & 3) << 2;
  const int tx4 = (tid & 15) << 2;
  const int ty4 = (tid >> 4) << 2;
  float accg[4][4] = {{0.f}};
  float acco[4][4] = {{0.f}};

  for (int kc = 0; kc < 512; kc += 16){
    float4 a1 = ld4(&h  [(size_t)(m0+r)*512 + kc + c4]);
    float4 a2 = ld4(&rdo[(size_t)(m0+r)*512 + kc + c4]);
    float4 w1 = ld4(&Wg [(size_t)(n0+r)*512 + kc + c4]);
    float4 w2 = ld4(&Wo [(size_t)(n0+r)*512 + kc + c4]);
    __syncthreads();
    Ag[c4+0][r]=a1.x; Ag[c4+1][r]=a1.y; Ag[c4+2][r]=a1.z; Ag[c4+3][r]=a1.w;
    Ao[c4+0][r]=a2.x; Ao[c4+1][r]=a2.y; Ao[c4+2][r]=a2.z; Ao[c4+3][r]=a2.w;
    Bg[c4+0][r]=w1.x; Bg[c4+1][r]=w1.y; Bg[c4+2][r]=w1.z; Bg[c4+3][r]=w1.w;
    Bo[c4+0][r]=w2.x; Bo[c4+1][r]=w2.y; Bo[c4+2][r]=w2.z; Bo[c4+3][r]=w2.w;
    __syncthreads();
#pragma unroll
    for (int k = 0; k < 16; ++k){
      float4 ag = ld4(&Ag[k][ty4]);
      float4 ao = ld4(&Ao[k][ty4]);
      float4 bg = ld4(&Bg[k][tx4]);
      float4 bo = ld4(&Bo[k][tx4]);
      accg[0][0]+=ag.x*bg.x; accg[0][1]+=ag.x*bg.y; accg[0][2]+=ag.x*bg.z; accg[0][3]+=ag.x*bg.w;
      accg[1][0]+=ag.y*bg.x; accg[1][1]+=ag.y*bg.y; accg[1][2]+=ag.y*bg.z; accg[1][3]+=ag.y*bg.w;
      accg[2][0]+=ag.z*bg.x; accg[2][1]+=ag.z*bg.y; accg[2][2]+=ag.z*bg.z; accg[2][3]+=ag.z*bg.w;
      accg[3][0]+=ag.w*bg.x; accg[3][1]+=ag.w*bg.y; accg[3][2]+=ag.w*bg.z; accg[3][3]+=ag.w*bg.w;
      acco[0][0]+=ao.x*bo.x; acco[0][1]+=ao.x*bo.y; acco[0][2]+=ao.x*bo.z; acco[0][3]+=ao.x*bo.w;
      acco[1][0]+=ao.y*bo.x; acco[1][1]+=ao.y*bo.y; acco[1][2]+=ao.y*bo.z; acco[1][3]+=ao.y*bo.w;
      acco[2][0]+=ao.z*bo.x; acco[2][1]+=ao.z*bo.y; acco[2][2]+=ao.z*bo.z; acco[2][3]+=ao.z*bo.w;
      acco[3][0]+=ao.w*bo.x; acco[3][1]+=ao.w*bo.y; acco[3][2]+=ao.w*bo.z; acco[3][3]+=ao.w*bo.w;
    }
  }
#pragma unroll
  for (int i = 0; i < 4; ++i){
    float4 cv;
    cv.x = acco[i][0] / (1.f + expf(-accg[i][0]));
    cv.y = acco[i][1] / (1.f + expf(-accg[i][1]));
    cv.z = acco[i][2] / (1.f + expf(-accg[i][2]));
    cv.w = acco[i][3] / (1.f + expf(-accg[i][3]));
    st4(&C[(size_t)(m0+ty4+i)*512 + n0 + tx4], cv);
  }
}

// ---------------------------------------------------------------------------
// A3: fused per-bt elementwise + cross-head precompute.
// ---------------------------------------------------------------------------
__global__ __launch_bounds__(256) void ew2_kernel(
    float* __restrict__ khat, float* __restrict__ kvk, float* __restrict__ kvv,
    float* __restrict__ pre2, const float* __restrict__ h,
    const float* __restrict__ hh_bw, const float* __restrict__ hh_bb)
{
  const int bt = blockIdx.x;
  const int tid = threadIdx.x;
  const int wid = tid >> 6, lane = tid & 63;
  float* k0p  = khat + (size_t)bt*D_;
  float* k1p  = khat + (size_t)BT_*D_ + (size_t)bt*D_;
  float* vk0p = kvk  + (size_t)bt*D_;
  float* vk1p = kvk  + (size_t)BT_*D_ + (size_t)bt*D_;
  float* vv0p = kvv  + (size_t)bt*D_;
  float* vv1p = kvv  + (size_t)BT_*D_ + (size_t)bt*D_;
  const float* hp  = h + (size_t)bt*D_;

  float s0[2], s1[2];
  float n0 = 0.f, n1 = 0.f, bd0 = 0.f, bd1 = 0.f;
#pragma unroll
  for (int q = 0; q < 2; ++q){
    int d = tid + q*256;
    float x0 = k0p[d], x1 = k1p[d], hv = hp[d];
    float v0 = x0 / (1.f + expf(-x0));
    float v1 = x1 / (1.f + expf(-x1));
    s0[q] = v0; s1[q] = v1;
    n0 += v0*v0; n1 += v1*v1;
    bd0 += hv*hh_bw[d]; bd1 += hv*hh_bw[D_ + d];
  }
  __shared__ float4 rb[4];
  float4 acc = make_float4(wred(n0), wred(n1), wred(bd0), wred(bd1));
  if (lane == 0) rb[wid] = acc;
  __syncthreads();
  float4 t0 = rb[0], t1 = rb[1], t2 = rb[2], t3 = rb[3];
  n0 = t0.x+t1.x+t2.x+t3.x; n1 = t0.y+t1.y+t2.y+t3.y;
  bd0 = t0.z+t1.z+t2.z+t3.z; bd1 = t0.w+t1.w+t2.w+t3.w;
  float inv0 = 1.f / fmaxf(sqrtf(n0), 1e-12f);
  float inv1 = 1.f / fmaxf(sqrtf(n1), 1e-12f);
  float be0 = 2.f / (1.f + expf(-(bd0 + hh_bb[0])));
  float be1 = 2.f / (1.f + expf(-(bd1 + hh_bb[1])));

  float c01 = 0.f, dK = 0.f, dV = 0.f;
#pragma unroll
  for (int q = 0; q < 2; ++q){
    int d = tid + q*256;
    float kh0 = s0[q]*inv0, kh1 = s1[q]*inv1;
    float u0K = s0[q]*vk0p[d], u1K = s1[q]*vk1p[d];
    float u0V = s0[q]*vv0p[d], u1V = s1[q]*vv1p[d];
    k0p[d] = kh0; k1p[d] = kh1;
    vk0p[d] = be0*u0K + be1*u1K;
    vv0p[d] = be0*u0V + be1*u1V;
    c01 += kh1*kh0; dK += kh1*u0K; dV += kh1*u0V;
  }
  __syncthreads();
  float4 acc2 = make_float4(wred(c01), wred(dK), wred(dV), 0.f);
  if (lane == 0) rb[wid] = acc2;
  __syncthreads();
  if (tid == 0){
    float4 a = rb[0], b = rb[1], c = rb[2], d = rb[3];
    pre2[(size_t)bt*8+0] = a.x+b.x+c.x+d.x;
    pre2[(size_t)bt*8+1] = a.y+b.y+c.y+d.y;
    pre2[(size_t)bt*8+2] = a.z+b.z+c.z+d.z;
    pre2[(size_t)bt*8+3] = be0;
    pre2[(size_t)bt*8+4] = be1;
  }
}

// ---------------------------------------------------------------------------
// B: sequential scan v8 — one barrier/step; register staging; uniform
// t+2 meta loads hoisted into A-phase to shorten the post-barrier tail.
// ---------------------------------------------------------------------------
__global__ __launch_bounds__(512) void scan_kernel(
    float* __restrict__ Ks, float* __restrict__ Vs,
    const float* __restrict__ khat, const float* __restrict__ ucKp,
    const float* __restrict__ ucVp, const float* __restrict__ pre2,
    const float* __restrict__ metab, const float2* __restrict__ zr,
    const float* __restrict__ h, float* __restrict__ readout,
    float* __restrict__ o_widx, float* __restrict__ o_ridx)
{
  __shared__ __align__(16) float Vr_s[2][TOPK_][D_];
  __shared__ float2 rel2_s[2][TOPK_];

  const int b = blockIdx.x;
  const int tid = threadIdx.x;
  const int s = tid >> 6, lane = tid & 63;
  const int l4 = lane * 4;
  const float scale = 0.044194173824159216f;   // 1/sqrt(512)

  float* Ksb = Ks + (size_t)b*M_*D_;
  float* Vsb = Vs + (size_t)b*M_*D_;
  const float* kh0p = khat;
  const float* kh1p = khat + (size_t)BT_*D_;
  const float4* mb = (const float4*)metab;

  // ---- prologue ----
  const int bt0 = b*T_;
  size_t o0 = (size_t)bt0*D_ + l4;
  float4 c_kh0a = ld4(kh0p+o0), c_kh0b = ld4(kh0p+o0+256);
  float4 c_kh1a = ld4(kh1p+o0), c_kh1b = ld4(kh1p+o0+256);
  float4 c_uKa  = ld4(ucKp+o0), c_uKb  = ld4(ucKp+o0+256);
  float4 c_uVa  = ld4(ucVp+o0), c_uVb  = ld4(ucVp+o0+256);

  float4 me   = mb[bt0*TOPK_ + s];
  float4 me_n = mb[(bt0+1)*TOPK_ + s];
  float4 pm   = ld4(&pre2[(size_t)bt0*8]);
  float  be1v = pre2[(size_t)bt0*8+4];
  float4 pm_n = ld4(&pre2[(size_t)(bt0+1)*8]);
  float  be1_n= pre2[(size_t)(bt0+1)*8+4];
  float2 zr2   = zr[(size_t)bt0*TOPK_ + s];
  float2 zr2_n = zr[(size_t)(bt0+1)*TOPK_ + s];

  int mi = __float_as_int(me.x);
  float4 K0 = ld4(&Ksb[(size_t)mi*D_ + l4]);
  float4 K1 = ld4(&Ksb[(size_t)mi*D_ + 256 + l4]);
  float4 V0 = ld4(&Vsb[(size_t)mi*D_ + l4]);
  float4 V1 = ld4(&Vsb[(size_t)mi*D_ + 256 + l4]);

#pragma unroll 2
  for (int t = 0; t < T_; ++t){
    const int bt = b*T_ + t;
    const float dec = me.z;
    const int   ri  = __float_as_int(me.w);
    mi = __float_as_int(me.x);

    // ---------------- A(t) ----------------
    const int btn  = (t+1 < T_) ? bt+1 : bt;
    const int btnn = (t+2 < T_) ? bt+2 : b*T_+T_-1;
    size_t on = (size_t)btn*D_ + l4;
    float4 n_kh0a = ld4(kh0p+on), n_kh0b = ld4(kh0p+on+256);
    float4 n_kh1a = ld4(kh1p+on), n_kh1b = ld4(kh1p+on+256);
    float4 n_uKa  = ld4(ucKp+on), n_uKb  = ld4(ucKp+on+256);
    float4 n_uVa  = ld4(ucVp+on), n_uVb  = ld4(ucVp+on+256);
    float4 HTa = ld4(h + (size_t)bt*D_ + l4);      // for B's read-dot
    float4 HTb = ld4(h + (size_t)bt*D_ + 256 + l4);
    // uniform t+2 meta (barrier-independent; hoisted out of B)
    float4 me_nn = mb[btnn*TOPK_ + s];
    float4 pm_nn = ld4(&pre2[(size_t)btnn*8]);
    float  be1nn = pre2[(size_t)btnn*8+4];
    float2 zr2nn = zr[(size_t)btnn*TOPK_ + s];

    // fused 2-head state update
    K0 = scl4(K0,dec); K1 = scl4(K1,dec);
    V0 = scl4(V0,dec); V1 = scl4(V1,dec);
    float aK = wredd(dot4(K0,c_kh0a) + dot4(K1,c_kh0b));
    float bK = wredd(dot4(K0,c_kh1a) + dot4(K1,c_kh1b));
    float aV = wredd(dot4(V0,c_kh0a) + dot4(V1,c_kh0b));
    float bV = wredd(dot4(V0,c_kh1a) + dot4(V1,c_kh1b));
    float p0K = pm.w*aK, p1K = be1v*(bK + pm.w*(pm.y - aK*pm.x));
    float p0V = pm.w*aV, p1V = be1v*(bV + pm.w*(pm.z - aV*pm.x));
    K0.x += c_uKa.x - p0K*c_kh0a.x - p1K*c_kh1a.x;
    K0.y += c_uKa.y - p0K*c_kh0a.y - p1K*c_kh1a.y;
    K0.z += c_uKa.z - p0K*c_kh0a.z - p1K*c_kh1a.z;
    K0.w += c_uKa.w - p0K*c_kh0a.w - p1K*c_kh1a.w;
    K1.x += c_uKb.x - p0K*c_kh0b.x - p1K*c_kh1b.x;
    K1.y += c_uKb.y - p0K*c_kh0b.y - p1K*c_kh1b.y;
    K1.z += c_uKb.z - p0K*c_kh0b.z - p1K*c_kh1b.z;
    K1.w += c_uKb.w - p0K*c_kh0b.w - p1K*c_kh1b.w;
    V0.x += c_uVa.x - p0V*c_kh0a.x - p1V*c_kh1a.x;
    V0.y += c_uVa.y - p0V*c_kh0a.y - p1V*c_kh1a.y;
    V0.z += c_uVa.z - p0V*c_kh0a.z - p1V*c_kh1a.z;
    V0.w += c_uVa.w - p0V*c_kh0a.w - p1V*c_kh1a.w;
    V1.x += c_uVb.x - p0V*c_kh0b.x - p1V*c_kh1b.x;
    V1.y += c_uVb.y - p0V*c_kh0b.y - p1V*c_kh1b.y;
    V1.z += c_uVb.z - p0V*c_kh0b.z - p1V*c_kh1b.z;
    V1.w += c_uVb.w - p0V*c_kh0b.w - p1V*c_kh1b.w;

    st4(&Ksb[(size_t)mi*D_ + l4], K0); st4(&Ksb[(size_t)mi*D_ + 256 + l4], K1);
    st4(&Vsb[(size_t)mi*D_ + l4], V0); st4(&Vsb[(size_t)mi*D_ + 256 + l4], V1);

    __syncthreads();   // THE barrier: scatters drained & visible

    // ---------------- B(t) ----------------
    float4 RK0 = ld4(&Ksb[(size_t)ri*D_ + l4]);
    float4 RK1 = ld4(&Ksb[(size_t)ri*D_ + 256 + l4]);
    float4 RV0 = ld4(&Vsb[(size_t)ri*D_ + l4]);
    float4 RV1 = ld4(&Vsb[(size_t)ri*D_ + 256 + l4]);
    const int mi_n = __float_as_int(me_n.x);
    float4 nK0 = ld4(&Ksb[(size_t)mi_n*D_ + l4]);
    float4 nK1 = ld4(&Ksb[(size_t)mi_n*D_ + 256 + l4]);
    float4 nV0 = ld4(&Vsb[(size_t)mi_n*D_ + l4]);
    float4 nV1 = ld4(&Vsb[(size_t)mi_n*D_ + 256 + l4]);

    // readout(t-1): overlaps the loads above
    if (t > 0){
      const int pp = (t-1) & 1;
      float2 rz[TOPK_];
#pragma unroll
      for (int i = 0; i < TOPK_; ++i) rz[i] = rel2_s[pp][i];
      float mx = rz[0].x;
#pragma unroll
      for (int i = 1; i < TOPK_; ++i) mx = fmaxf(mx, rz[i].x);
      float smm = 0.f, r = 0.f;
#pragma unroll
      for (int i = 0; i < TOPK_; ++i){
        float ev = __expf(rz[i].x - mx); smm += ev;
        r += ev * rz[i].y * Vr_s[pp][i][tid];
      }
      readout[(size_t)(bt-1)*D_ + tid] = r * __builtin_amdgcn_rcpf(smm);
    }

    // resolve(t)
    float dt = wredd(dot4(RK0,HTa) + dot4(RK1,HTb));
    if (lane == 0)
      rel2_s[t&1][s] = make_float2(dt * scale * zr2.x, zr2.y);
    st4(&Vr_s[t&1][s][l4], RV0); st4(&Vr_s[t&1][s][256+l4], RV1);

    // rotate pipeline
    K0=nK0; K1=nK1; V0=nV0; V1=nV1;
    me=me_n; pm=pm_n; be1v=be1_n; zr2=zr2_n;
    me_n=me_nn; pm_n=pm_nn; be1_n=be1nn; zr2_n=zr2nn;
    c_kh0a=n_kh0a; c_kh0b=n_kh0b; c_kh1a=n_kh1a; c_kh1b=n_kh1b;
    c_uKa=n_uKa; c_uKb=n_uKb; c_uVa=n_uVa; c_uVb=n_uVb;
  }

  // ---- epilogue: readout(T-1) ----
  __syncthreads();
  {
    const int btL = b*T_ + T_ - 1;
    const int pp = (T_-1) & 1;
    float2 rz[TOPK_];
#pragma unroll
    for (int i = 0; i < TOPK_; ++i) rz[i] = rel2_s[pp][i];
    float mx = rz[0].x;
#pragma unroll
    for (int i = 1; i < TOPK_; ++i) mx = fmaxf(mx, rz[i].x);
    float smm = 0.f, r = 0.f;
#pragma unroll
    for (int i = 0; i < TOPK_; ++i){
      float ev = __expf(rz[i].x - mx); smm += ev;
      r += ev * rz[i].y * Vr_s[pp][i][tid];
    }
    readout[(size_t)btL*D_ + tid] = r * __builtin_amdgcn_rcpf(smm);

    if (tid < TOPK_){
      float4 m = mb[btL*TOPK_ + tid];
      o_widx[b*TOPK_+tid] = (float)__float_as_int(m.x);
      o_ridx[b*TOPK_+tid] = (float)__float_as_int(m.w);
    }
  }
}

// ---------------------------------------------------------------------------
extern "C" void kernel_launch(void* const* d_in, const int* in_sizes, int n_in,
                              void* d_out, int out_size, void* d_ws, size_t ws_size,
                              hipStream_t stream)
{
  (void)in_sizes; (void)n_in; (void)out_size; (void)ws_size;
  const float* h       = (const float*)d_in[0];
  const float* K_slots = (const float*)d_in[1];
  const float* V_slots = (const float*)d_in[2];
  const float* z_K     = (const float*)d_in[3];
  const float* z_V     = (const float*)d_in[4];
  const float* W_k     = (const float*)d_in[5];
  const float* W_q     = (const float*)d_in[6];
  const float* ltw     = (const float*)d_in[7];
  const float* ltr     = (const float*)d_in[8];
  const float* hh_k    = (const float*)d_in[9];
  const float* hh_vk   = (const float*)d_in[10];
  const float* hh_vv   = (const float*)d_in[11];
  const float* hh_bw   = (const float*)d_in[12];
  const float* hh_bb   = (const float*)d_in[13];
  const float* gamma   = (const float*)d_in[14];
  const float* W_out   = (const float*)d_in[15];
  const float* W_gate  = (const float*)d_in[16];

  float* out    = (float*)d_out;
  float* o_outs = out;                 // (B,T,D)   524288
  float* o_Ks   = out + 524288;        // (B,M,D)  1048576
  float* o_Vs   = out + 1572864;       // (B,M,D)  1048576
  float* o_zK   = out + 2621440;       // (B,M)       2048
  float* o_zV   = out + 2623488;       // (B,M)       2048
  float* o_widx = out + 2625536;       // (B,8)         64
  float* o_ridx = out + 2625600;       // (B,8)         64

  float* ws    = (float*)d_ws;
  float* khat  = ws;                          // 2 * BT * D
  float* kvk   = ws + 2*(size_t)BT_*D_;       // 2 * BT * D
  float* kvv   = kvk + 2*(size_t)BT_*D_;      // 2 * BT * D
  float* rdo   = kvv + 2*(size_t)BT_*D_;      // BT * D
  float* metab = rdo + (size_t)BT_*D_;        // BT * 8 * 4
  float* pre2  = metab + (size_t)BT_*TOPK_*4; // BT * 8
  float2* zrb  = (float2*)(pre2 + (size_t)BT_*8); // BT * 8 float2

  (void)hipMemcpyAsync(o_Ks, K_slots, sizeof(float)*(size_t)B_*M_*D_,
                       hipMemcpyDeviceToDevice, stream);
  (void)hipMemcpyAsync(o_Vs, V_slots, sizeof(float)*(size_t)B_*M_*D_,
                       hipMemcpyDeviceToDevice, stream);

  addr_kernel<<<BT_, 64, 0, stream>>>(h, W_k, W_q, ltw, ltr, gamma, metab);

  GemmPtrs p{};
  p.W[0] = hh_k;           p.C[0] = khat;
  p.W[1] = hh_k + 262144;  p.C[1] = khat + (size_t)BT_*D_;
  p.W[2] = hh_vk;          p.C[2] = kvk;
  p.W[3] = hh_vk + 262144; p.C[3] = kvk + (size_t)BT_*D_;
  p.W[4] = hh_vv;          p.C[4] = kvv;
  p.W[5] = hh_vv + 262144; p.C[5] = kvv + (size_t)BT_*D_;
  // grid.z==6 slice (blockIdx.y==0) runs the fused z-recurrence scan
  gemm_nt<<<dim3(8,16,7), 256, 0, stream>>>(h, p, z_K, z_V, metab, zrb,
                                            o_zK, o_zV);

  ew2_kernel<<<BT_, 256, 0, stream>>>(khat, kvk, kvv, pre2, h, hh_bw, hh_bb);

  scan_kernel<<<B_, 512, 0, stream>>>(o_Ks, o_Vs, khat, kvk, kvv,
                                      pre2, metab, zrb, h, rdo,
                                      o_widx, o_ridx);

  gemm_out<<<dim3(8,16), 256, 0, stream>>>(h, rdo, W_gate, W_out, o_outs);
}